// Round 17
// baseline (146.990 us; speedup 1.0000x reference)
//
#include <hip/hip_runtime.h>
#include <hip/hip_bf16.h>

typedef __bf16 bf16x8 __attribute__((ext_vector_type(8)));
typedef __bf16 bf16x4 __attribute__((ext_vector_type(4)));
typedef float  f32x4  __attribute__((ext_vector_type(4)));

constexpr int NN = 16384;
constexpr int EE = 64;
constexpr int DD = 128;
constexpr int EG  = 8;     // experts per block
constexpr int BR  = 256;   // n-rows per block (halves W L2 traffic vs 128)

// ---------- pre-pass 1: X f32 -> bf16 row-major [N][D] ----------
__global__ __launch_bounds__(256)
void cvt_x(const float* __restrict__ X, __bf16* __restrict__ Xb) {
    int i = blockIdx.x * 256 + threadIdx.x;
    const float4* src = (const float4*)X;
    float4 v0 = src[2*i], v1 = src[2*i+1];
    bf16x8 p;
    p[0]=(__bf16)v0.x; p[1]=(__bf16)v0.y; p[2]=(__bf16)v0.z; p[3]=(__bf16)v0.w;
    p[4]=(__bf16)v1.x; p[5]=(__bf16)v1.y; p[6]=(__bf16)v1.z; p[7]=(__bf16)v1.w;
    ((bf16x8*)Xb)[i] = p;
}

// ---------- pre-pass 2: W[e][d][f] f32 -> per-expert SWIZZLED bf16 [f][d] ----------
// Element (f,d) at byte (f*256 + d*2) ^ ((f&7)<<4) within expert's 32KB.
// global_load_lds copies linearly; ds_read applies the same XOR (rule #21).
__global__ __launch_bounds__(256)
void cvt_wt(const float* __restrict__ W, __bf16* __restrict__ WTs) {
    __shared__ __bf16 T[DD][DD + 1];
    const int e = blockIdx.x;
    const int t = threadIdx.x;
    const float4* Wg = (const float4*)(W + (size_t)e * DD * DD);
    #pragma unroll
    for (int i = 0; i < 16; ++i) {
        int ft = i * 256 + t;
        int d = ft >> 5, f0 = (ft & 31) * 4;
        float4 v = Wg[ft];
        T[f0+0][d] = (__bf16)v.x;
        T[f0+1][d] = (__bf16)v.y;
        T[f0+2][d] = (__bf16)v.z;
        T[f0+3][d] = (__bf16)v.w;
    }
    __syncthreads();
    char* out = (char*)WTs + (size_t)e * DD * DD * 2;
    #pragma unroll
    for (int i = 0; i < 8; ++i) {
        int ft = i * 256 + t;
        int f = ft >> 4, d0 = (ft & 15) * 8;
        bf16x8 p;
        #pragma unroll
        for (int j = 0; j < 8; ++j) p[j] = T[f][d0 + j];
        int off = f * 256 + d0 * 2;
        off ^= (f & 7) << 4;
        *(bf16x8*)(out + off) = p;
    }
}

__device__ __forceinline__ void gll16(const void* g, void* l) {
    __builtin_amdgcn_global_load_lds(
        (const __attribute__((address_space(1))) void*)g,
        (__attribute__((address_space(3))) void*)l, 16, 0, 0);
}

// ---------- main GEMM: 512 thr / 8 waves, 256 rows x 8 experts ----------
// CHANGE vs R13 (isolated lever): block n-tile 128 -> 256 rows. Each W tile
// staged once serves 2x the rows -> W L2->LDS traffic halves (2.0 -> 1.0 GB
// per run), relieving the ~86%-utilized per-XCD L2 read path. Wave (wr 0..3,
// wc 0..1) = 64 rows x 64 cols; a[4][4], acc[4][4]. Epilogue in two 32-row
// sub-phases reusing the wave-private 8 KB obuf. Bias via LDS (no vm loads
// in loop); end-of-iter barrier = vmcnt(16) (retire 4 glls, keep this
// iter's 16 stores in flight).
__global__ __launch_bounds__(512, 1)
void experts_gemm_ls(const __bf16* __restrict__ Xb,
                     const __bf16* __restrict__ WTs,
                     const float* __restrict__ Bias,
                     float* __restrict__ O)
{
    __shared__ __align__(16) char lds[2*32768 + 65536 + 4096]; // Wdbuf|obuf|bias
    const int t    = threadIdx.x;
    const int lane = t & 63, w = t >> 6;          // w 0..7
    const int l15  = lane & 15, kg = lane >> 4;
    const int wr   = w >> 1, wc = w & 1;          // 4 row-groups x 2 col-halves
    const int eg   = blockIdx.x & (EE/EG - 1);
    const int n0   = (blockIdx.x >> 3) * BR;
    const int e0   = eg * EG;
    char* obuf = lds + 65536 + w * 8192;          // wave-private 8 KB
    char* blds = lds + 131072;                    // 8 experts x 512 B bias

    // X fragments, loaded once: rows n0 + wr*64 + m*16 + l15, k = kk*32+kg*8
    bf16x8 a[4][4];
    {
        const __bf16* Xp = Xb + (size_t)(n0 + wr*64 + l15) * DD + kg*8;
        #pragma unroll
        for (int m = 0; m < 4; ++m)
            #pragma unroll
            for (int kk = 0; kk < 4; ++kk)
                a[m][kk] = *(const bf16x8*)(Xp + m*16*DD + kk*32);
    }

    // prologue: stage bias for all EG experts -> LDS (4 KB)
    if (t < 256) {
        f32x4 v = ((const f32x4*)(Bias + e0*DD))[t];
        *(f32x4*)(blds + t*16) = v;
    }

    // prologue: stage W[e0] -> buffer 0 (each wave stages 4 KB via 4 glls)
    {
        const char* src = (const char*)WTs + (size_t)e0 * 32768 + w*4096 + lane*16;
        char* dst = lds + w*4096;
        #pragma unroll
        for (int i = 0; i < 4; ++i) gll16(src + i*1024, dst + i*1024);
    }
    __syncthreads();

    int cur = 0;
    for (int ei = 0; ei < EG; ++ei) {
        const int e = e0 + ei;

        // prefetch next expert's W into the other buffer (stays in flight)
        if (ei + 1 < EG) {
            const char* src = (const char*)WTs + (size_t)(e+1) * 32768 + w*4096 + lane*16;
            char* dst = lds + (cur ^ 1) * 32768 + w*4096;
            #pragma unroll
            for (int i = 0; i < 4; ++i) gll16(src + i*1024, dst + i*1024);
        }

        // bias via LDS (lgkm only — no vmcnt wait in the loop)
        f32x4 acc[4][4];
        #pragma unroll
        for (int n = 0; n < 4; ++n) {
            f32x4 bv = *(const f32x4*)(blds + ei*512 + wc*256 + n*64 + kg*16);
            #pragma unroll
            for (int m = 0; m < 4; ++m) acc[m][n] = bv;
        }

        // compute: 4 kk x {4 b ds_reads, 16 MFMA}
        const char* buf = lds + cur * 32768;
        #pragma unroll
        for (int kk = 0; kk < 4; ++kk) {
            bf16x8 b[4];
            #pragma unroll
            for (int n = 0; n < 4; ++n) {
                int f = wc*64 + n*16 + l15;
                int off = f*256 + (kk*32 + kg*8)*2;
                off ^= (l15 & 7) << 4;
                b[n] = *(const bf16x8*)(buf + off);
            }
            #pragma unroll
            for (int m = 0; m < 4; ++m)
                #pragma unroll
                for (int n = 0; n < 4; ++n)
                    acc[m][n] = __builtin_amdgcn_mfma_f32_16x16x32_bf16(
                        b[n], a[m][kk], acc[m][n], 0, 0, 0);
        }

        // epilogue: two 32-row sub-phases through the wave-private 8 KB obuf
        #pragma unroll
        for (int mh = 0; mh < 2; ++mh) {
            if (mh == 1) {
                // WAR fence: sub-phase 0's readback must complete before
                // overwriting obuf (lgkm only — stores keep draining)
                __builtin_amdgcn_sched_barrier(0);
                asm volatile("s_waitcnt lgkmcnt(0)" ::: "memory");
                __builtin_amdgcn_sched_barrier(0);
            }
            // stage: m = 2*mh, 2*mh+1 -> local rows 0..31
            #pragma unroll
            for (int mm = 0; mm < 2; ++mm) {
                int m = mh*2 + mm;
                #pragma unroll
                for (int n = 0; n < 4; ++n) {
                    int row = mm*16 + l15;
                    int off = row*256 + n*64 + kg*16;
                    off ^= (row & 7) << 4;
                    *(f32x4*)(obuf + off) = acc[m][n];
                }
            }
            // readback + 256 B-contiguous stores
            {
                const int ro = lane >> 4, c16 = lane & 15;
                #pragma unroll
                for (int rg = 0; rg < 8; ++rg) {
                    int row = rg*4 + ro;
                    int off = row*256 + c16*16;
                    off ^= (row & 7) << 4;
                    f32x4 v = *(const f32x4*)(obuf + off);
                    *(f32x4*)(O + (size_t)(n0 + wr*64 + mh*32 + row) * (EE*DD)
                                + e*DD + wc*64 + c16*4) = v;
                }
            }
        }

        // counted barrier: retire the 4 glls (next W buffer ready); keep the
        // 16 newest ops (this expert's stores) in flight.
        if (ei + 1 < EG) {
            __builtin_amdgcn_sched_barrier(0);
            asm volatile("s_waitcnt vmcnt(16)" ::: "memory");
            __builtin_amdgcn_s_barrier();
            __builtin_amdgcn_sched_barrier(0);
        }
        cur ^= 1;
    }
}

// ---------- fallback (round-0 kernel, used if ws too small) ----------
__global__ __launch_bounds__(256, 2)
void experts_gemm_fb(const float* __restrict__ X,
                     const float* __restrict__ W,
                     const float* __restrict__ Bias,
                     float* __restrict__ O)
{
    constexpr int BM = 128;
    __shared__ __align__(16) char lds[BM*DD*2 + DD*DD*2];
    __bf16* As = (__bf16*)lds;
    __bf16* Bs = (__bf16*)(lds + BM*DD*2);

    const int t   = threadIdx.x;
    const int e   = blockIdx.x & (EE - 1);
    const int n0  = (blockIdx.x >> 6) * BM;

    {
        const float4* Xg = (const float4*)(X + (size_t)n0 * DD);
        #pragma unroll
        for (int i = 0; i < 16; ++i) {
            int ft = i * 256 + t;
            float4 v = Xg[ft];
            int n = ft >> 5, d0 = (ft & 31) << 2;
            bf16x4 p;
            p[0]=(__bf16)v.x; p[1]=(__bf16)v.y; p[2]=(__bf16)v.z; p[3]=(__bf16)v.w;
            int off = n * 256 + d0 * 2;
            off ^= (n & 7) << 4;
            *(bf16x4*)((char*)As + off) = p;
        }
    }
    {
        const float4* Wg = (const float4*)(W + (size_t)e * DD * DD);
        #pragma unroll
        for (int i = 0; i < 4; ++i) {
            int bb = i * 256 + t;
            int db = bb >> 5, fb = bb & 31;
            float4 r0 = Wg[(db*4+0)*32 + fb];
            float4 r1 = Wg[(db*4+1)*32 + fb];
            float4 r2 = Wg[(db*4+2)*32 + fb];
            float4 r3 = Wg[(db*4+3)*32 + fb];
            const float* q0=(const float*)&r0; const float* q1=(const float*)&r1;
            const float* q2=(const float*)&r2; const float* q3=(const float*)&r3;
            #pragma unroll
            for (int j = 0; j < 4; ++j) {
                bf16x4 p;
                p[0]=(__bf16)q0[j]; p[1]=(__bf16)q1[j];
                p[2]=(__bf16)q2[j]; p[3]=(__bf16)q3[j];
                int f = fb * 4 + j;
                int off = f * 256 + db * 8;
                off ^= (f & 7) << 4;
                *(bf16x4*)((char*)Bs + off) = p;
            }
        }
    }
    __syncthreads();

    const int lane = t & 63, w = t >> 6;
    const int wr = w >> 1, wc = w & 1;
    const int l15 = lane & 15, kg = lane >> 4;

    f32x4 acc[4][4];
    #pragma unroll
    for (int m = 0; m < 4; ++m)
        #pragma unroll
        for (int n = 0; n < 4; ++n) {
            acc[m][n][0]=0.f; acc[m][n][1]=0.f; acc[m][n][2]=0.f; acc[m][n][3]=0.f;
        }

    float bias[4];
    #pragma unroll
    for (int n = 0; n < 4; ++n) bias[n] = Bias[e*DD + wc*64 + n*16 + l15];

    #pragma unroll
    for (int kk = 0; kk < 4; ++kk) {
        int koff = kk * 32 + kg * 8;
        bf16x8 av[4], bvv[4];
        #pragma unroll
        for (int m = 0; m < 4; ++m) {
            int row = wr*64 + m*16 + l15;
            int off = row * 256 + koff * 2;
            off ^= (row & 7) << 4;
            av[m] = *(const bf16x8*)((const char*)As + off);
        }
        #pragma unroll
        for (int n = 0; n < 4; ++n) {
            int col = wc*64 + n*16 + l15;
            int off = col * 256 + koff * 2;
            off ^= (col & 7) << 4;
            bvv[n] = *(const bf16x8*)((const char*)Bs + off);
        }
        #pragma unroll
        for (int m = 0; m < 4; ++m)
            #pragma unroll
            for (int n = 0; n < 4; ++n)
                acc[m][n] = __builtin_amdgcn_mfma_f32_16x16x32_bf16(
                    av[m], bvv[n], acc[m][n], 0, 0, 0);
    }

    float* Op = O + (size_t)n0 * (EE*DD) + (size_t)e * DD;
    #pragma unroll
    for (int m = 0; m < 4; ++m)
        #pragma unroll
        for (int n = 0; n < 4; ++n) {
            int cg = wc*64 + n*16 + l15;
            #pragma unroll
            for (int r = 0; r < 4; ++r) {
                int rg = wr*64 + m*16 + kg*4 + r;
                Op[(size_t)rg * (EE*DD) + cg] = acc[m][n][r] + bias[n];
            }
        }
}

extern "C" void kernel_launch(void* const* d_in, const int* in_sizes, int n_in,
                              void* d_out, int out_size, void* d_ws, size_t ws_size,
                              hipStream_t stream) {
    const float* X = (const float*)d_in[0];
    const float* W = (const float*)d_in[1];
    const float* B = (const float*)d_in[2];
    float* O = (float*)d_out;

    const size_t xb_bytes = (size_t)NN * DD * sizeof(__bf16);      // 4 MiB
    const size_t wt_bytes = (size_t)EE * DD * DD * sizeof(__bf16); // 2 MiB

    if (ws_size >= xb_bytes + wt_bytes) {
        __bf16* Xb  = (__bf16*)d_ws;
        __bf16* WTs = (__bf16*)((char*)d_ws + xb_bytes);
        cvt_x<<<NN * DD / 8 / 256, 256, 0, stream>>>(X, Xb);
        cvt_wt<<<EE, 256, 0, stream>>>(W, WTs);
        experts_gemm_ls<<<(NN / BR) * (EE / EG), 512, 0, stream>>>(Xb, WTs, B, O);
    } else {
        experts_gemm_fb<<<(NN / 128) * EE, 256, 0, stream>>>(X, W, B, O);
    }
}

// Round 18
// 135.059 us; speedup vs baseline: 1.0883x; 1.0883x over previous
//
#include <hip/hip_runtime.h>
#include <hip/hip_bf16.h>

typedef __bf16 bf16x8 __attribute__((ext_vector_type(8)));
typedef __bf16 bf16x4 __attribute__((ext_vector_type(4)));
typedef float  f32x4  __attribute__((ext_vector_type(4)));

constexpr int NN = 16384;
constexpr int EE = 64;
constexpr int DD = 128;
constexpr int EG  = 8;     // experts per block

// ---------- pre-pass 1: X f32 -> bf16 row-major [N][D] ----------
__global__ __launch_bounds__(256)
void cvt_x(const float* __restrict__ X, __bf16* __restrict__ Xb) {
    int i = blockIdx.x * 256 + threadIdx.x;
    const float4* src = (const float4*)X;
    float4 v0 = src[2*i], v1 = src[2*i+1];
    bf16x8 p;
    p[0]=(__bf16)v0.x; p[1]=(__bf16)v0.y; p[2]=(__bf16)v0.z; p[3]=(__bf16)v0.w;
    p[4]=(__bf16)v1.x; p[5]=(__bf16)v1.y; p[6]=(__bf16)v1.z; p[7]=(__bf16)v1.w;
    ((bf16x8*)Xb)[i] = p;
}

// ---------- pre-pass 2: W[e][d][f] f32 -> per-expert SWIZZLED bf16 [f][d] ----------
// Element (f,d) at byte (f*256 + d*2) ^ ((f&7)<<4) within expert's 32KB.
// global_load_lds copies linearly; ds_read applies the same XOR (rule #21).
__global__ __launch_bounds__(256)
void cvt_wt(const float* __restrict__ W, __bf16* __restrict__ WTs) {
    __shared__ __bf16 T[DD][DD + 1];
    const int e = blockIdx.x;
    const int t = threadIdx.x;
    const float4* Wg = (const float4*)(W + (size_t)e * DD * DD);
    #pragma unroll
    for (int i = 0; i < 16; ++i) {
        int ft = i * 256 + t;
        int d = ft >> 5, f0 = (ft & 31) * 4;
        float4 v = Wg[ft];
        T[f0+0][d] = (__bf16)v.x;
        T[f0+1][d] = (__bf16)v.y;
        T[f0+2][d] = (__bf16)v.z;
        T[f0+3][d] = (__bf16)v.w;
    }
    __syncthreads();
    char* out = (char*)WTs + (size_t)e * DD * DD * 2;
    #pragma unroll
    for (int i = 0; i < 8; ++i) {
        int ft = i * 256 + t;
        int f = ft >> 4, d0 = (ft & 15) * 8;
        bf16x8 p;
        #pragma unroll
        for (int j = 0; j < 8; ++j) p[j] = T[f][d0 + j];
        int off = f * 256 + d0 * 2;
        off ^= (f & 7) << 4;
        *(bf16x8*)(out + off) = p;
    }
}

__device__ __forceinline__ void gll16(const void* g, void* l) {
    __builtin_amdgcn_global_load_lds(
        (const __attribute__((address_space(1))) void*)g,
        (__attribute__((address_space(3))) void*)l, 16, 0, 0);
}

// ---------- main GEMM: R13 structure + XCD-aware block remap (isolated) ----------
// 512 thr / 8 waves, 128 rows x 8 experts; wave (wr,wc) = 32 rows x 64 cols.
// REMAP: the 8 blocks covering the SAME 128 output rows (all 64 experts,
// interleaved 512 B segments in the same 32 KB row-spans) are spaced 8 apart
// in blockIdx -> same XCD under round-robin dispatch, co-resident within a
// 64-bid window. That XCD's L2 aggregates full dense rows before eviction ->
// dense sequential HBM write streams (fill-kernel-like) instead of 4 KB combs
// from 8 uncoordinated L2s.
__global__ __launch_bounds__(512, 1)
void experts_gemm_ls(const __bf16* __restrict__ Xb,
                     const __bf16* __restrict__ WTs,
                     const float* __restrict__ Bias,
                     float* __restrict__ O)
{
    __shared__ __align__(16) char lds[2*32768 + 65536 + 4096]; // Wdbuf|obuf|bias
    const int t    = threadIdx.x;
    const int lane = t & 63, w = t >> 6;          // w 0..7
    const int l15  = lane & 15, kg = lane >> 4;
    const int wr   = w >> 1, wc = w & 1;          // 4 row-groups x 2 col-halves
    // XCD-aware remap (bijective on [0,1024)): same-rows blocks 8 apart.
    const int eg   = (blockIdx.x >> 3) & 7;
    const int nt   = ((blockIdx.x >> 6) << 3) + (blockIdx.x & 7);
    const int n0   = nt * 128;
    const int e0   = eg * EG;
    char* obuf = lds + 65536 + w * 8192;          // wave-private 8 KB
    char* blds = lds + 131072;                    // 8 experts x 512 B bias

    // X fragments, loaded once: rows n0 + wr*32 + m*16 + l15, k = kk*32+kg*8
    bf16x8 a[2][4];
    {
        const __bf16* Xp = Xb + (size_t)(n0 + wr*32 + l15) * DD + kg*8;
        #pragma unroll
        for (int m = 0; m < 2; ++m)
            #pragma unroll
            for (int kk = 0; kk < 4; ++kk)
                a[m][kk] = *(const bf16x8*)(Xp + m*16*DD + kk*32);
    }

    // prologue: stage bias for all EG experts -> LDS (4 KB, one f32x4/thread)
    if (t < 256) {
        f32x4 v = ((const f32x4*)(Bias + e0*DD))[t];
        *(f32x4*)(blds + t*16) = v;
    }

    // prologue: stage W[e0] -> buffer 0 (each wave stages 4 KB via 4 glls)
    {
        const char* src = (const char*)WTs + (size_t)e0 * 32768 + w*4096 + lane*16;
        char* dst = lds + w*4096;
        #pragma unroll
        for (int i = 0; i < 4; ++i) gll16(src + i*1024, dst + i*1024);
    }
    __syncthreads();

    int cur = 0;
    for (int ei = 0; ei < EG; ++ei) {
        const int e = e0 + ei;

        // prefetch next expert's W into the other buffer (stays in flight)
        if (ei + 1 < EG) {
            const char* src = (const char*)WTs + (size_t)(e+1) * 32768 + w*4096 + lane*16;
            char* dst = lds + (cur ^ 1) * 32768 + w*4096;
            #pragma unroll
            for (int i = 0; i < 4; ++i) gll16(src + i*1024, dst + i*1024);
        }

        // bias via LDS (lgkm only — no vmcnt wait in the loop)
        f32x4 acc[2][4];
        #pragma unroll
        for (int n = 0; n < 4; ++n) {
            f32x4 bv = *(const f32x4*)(blds + ei*512 + wc*256 + n*64 + kg*16);
            acc[0][n] = bv; acc[1][n] = bv;
        }

        // compute
        const char* buf = lds + cur * 32768;
        #pragma unroll
        for (int kk = 0; kk < 4; ++kk) {
            bf16x8 b[4];
            #pragma unroll
            for (int n = 0; n < 4; ++n) {
                int f = wc*64 + n*16 + l15;
                int off = f*256 + (kk*32 + kg*8)*2;
                off ^= (l15 & 7) << 4;
                b[n] = *(const bf16x8*)(buf + off);
            }
            #pragma unroll
            for (int m = 0; m < 2; ++m)
                #pragma unroll
                for (int n = 0; n < 4; ++n)
                    acc[m][n] = __builtin_amdgcn_mfma_f32_16x16x32_bf16(
                        b[n], a[m][kk], acc[m][n], 0, 0, 0);
        }

        // stage acc -> wave-private obuf: row = m*16+l15 (0..31), 256 B/row
        #pragma unroll
        for (int m = 0; m < 2; ++m) {
            #pragma unroll
            for (int n = 0; n < 4; ++n) {
                int row = m*16 + l15;
                int off = row*256 + n*64 + kg*16;
                off ^= (row & 7) << 4;
                *(f32x4*)(obuf + off) = acc[m][n];
            }
        }
        // no barrier: same wave reads its own slice (lgkm-ordered)

        // readback + stores: per inst 4 rows x (16 lanes x 16 B = 256 B)
        {
            const int row_off = lane >> 4;       // 0..3
            const int c16 = lane & 15;           // 16 lanes -> 256 B run
            #pragma unroll
            for (int rg = 0; rg < 8; ++rg) {     // 32 rows / 4 per inst
                int row = rg*4 + row_off;
                int off = row*256 + c16*16;
                off ^= (row & 7) << 4;
                f32x4 v = *(const f32x4*)(obuf + off);
                *(f32x4*)(O + (size_t)(n0 + wr*32 + row) * (EE*DD)
                            + e*DD + wc*64 + c16*4) = v;
            }
        }

        // counted barrier: retire the 4 glls (next W buffer ready); keep the
        // 8 newest ops (this expert's stores) in flight.
        if (ei + 1 < EG) {
            __builtin_amdgcn_sched_barrier(0);
            asm volatile("s_waitcnt vmcnt(8)" ::: "memory");
            __builtin_amdgcn_s_barrier();
            __builtin_amdgcn_sched_barrier(0);
        }
        cur ^= 1;
    }
}

// ---------- fallback (round-0 kernel, used if ws too small) ----------
__global__ __launch_bounds__(256, 2)
void experts_gemm_fb(const float* __restrict__ X,
                     const float* __restrict__ W,
                     const float* __restrict__ Bias,
                     float* __restrict__ O)
{
    constexpr int BM = 128;
    __shared__ __align__(16) char lds[BM*DD*2 + DD*DD*2];
    __bf16* As = (__bf16*)lds;
    __bf16* Bs = (__bf16*)(lds + BM*DD*2);

    const int t   = threadIdx.x;
    const int e   = blockIdx.x & (EE - 1);
    const int n0  = (blockIdx.x >> 6) * BM;

    {
        const float4* Xg = (const float4*)(X + (size_t)n0 * DD);
        #pragma unroll
        for (int i = 0; i < 16; ++i) {
            int ft = i * 256 + t;
            float4 v = Xg[ft];
            int n = ft >> 5, d0 = (ft & 31) << 2;
            bf16x4 p;
            p[0]=(__bf16)v.x; p[1]=(__bf16)v.y; p[2]=(__bf16)v.z; p[3]=(__bf16)v.w;
            int off = n * 256 + d0 * 2;
            off ^= (n & 7) << 4;
            *(bf16x4*)((char*)As + off) = p;
        }
    }
    {
        const float4* Wg = (const float4*)(W + (size_t)e * DD * DD);
        #pragma unroll
        for (int i = 0; i < 4; ++i) {
            int bb = i * 256 + t;
            int db = bb >> 5, fb = bb & 31;
            float4 r0 = Wg[(db*4+0)*32 + fb];
            float4 r1 = Wg[(db*4+1)*32 + fb];
            float4 r2 = Wg[(db*4+2)*32 + fb];
            float4 r3 = Wg[(db*4+3)*32 + fb];
            const float* q0=(const float*)&r0; const float* q1=(const float*)&r1;
            const float* q2=(const float*)&r2; const float* q3=(const float*)&r3;
            #pragma unroll
            for (int j = 0; j < 4; ++j) {
                bf16x4 p;
                p[0]=(__bf16)q0[j]; p[1]=(__bf16)q1[j];
                p[2]=(__bf16)q2[j]; p[3]=(__bf16)q3[j];
                int f = fb * 4 + j;
                int off = f * 256 + db * 8;
                off ^= (f & 7) << 4;
                *(bf16x4*)((char*)Bs + off) = p;
            }
        }
    }
    __syncthreads();

    const int lane = t & 63, w = t >> 6;
    const int wr = w >> 1, wc = w & 1;
    const int l15 = lane & 15, kg = lane >> 4;

    f32x4 acc[4][4];
    #pragma unroll
    for (int m = 0; m < 4; ++m)
        #pragma unroll
        for (int n = 0; n < 4; ++n) {
            acc[m][n][0]=0.f; acc[m][n][1]=0.f; acc[m][n][2]=0.f; acc[m][n][3]=0.f;
        }

    float bias[4];
    #pragma unroll
    for (int n = 0; n < 4; ++n) bias[n] = Bias[e*DD + wc*64 + n*16 + l15];

    #pragma unroll
    for (int kk = 0; kk < 4; ++kk) {
        int koff = kk * 32 + kg * 8;
        bf16x8 av[4], bvv[4];
        #pragma unroll
        for (int m = 0; m < 4; ++m) {
            int row = wr*64 + m*16 + l15;
            int off = row * 256 + koff * 2;
            off ^= (row & 7) << 4;
            av[m] = *(const bf16x8*)((const char*)As + off);
        }
        #pragma unroll
        for (int n = 0; n < 4; ++n) {
            int col = wc*64 + n*16 + l15;
            int off = col * 256 + koff * 2;
            off ^= (col & 7) << 4;
            bvv[n] = *(const bf16x8*)((const char*)Bs + off);
        }
        #pragma unroll
        for (int m = 0; m < 4; ++m)
            #pragma unroll
            for (int n = 0; n < 4; ++n)
                acc[m][n] = __builtin_amdgcn_mfma_f32_16x16x32_bf16(
                    av[m], bvv[n], acc[m][n], 0, 0, 0);
    }

    float* Op = O + (size_t)n0 * (EE*DD) + (size_t)e * DD;
    #pragma unroll
    for (int m = 0; m < 4; ++m)
        #pragma unroll
        for (int n = 0; n < 4; ++n) {
            int cg = wc*64 + n*16 + l15;
            #pragma unroll
            for (int r = 0; r < 4; ++r) {
                int rg = wr*64 + m*16 + kg*4 + r;
                Op[(size_t)rg * (EE*DD) + cg] = acc[m][n][r] + bias[n];
            }
        }
}

extern "C" void kernel_launch(void* const* d_in, const int* in_sizes, int n_in,
                              void* d_out, int out_size, void* d_ws, size_t ws_size,
                              hipStream_t stream) {
    const float* X = (const float*)d_in[0];
    const float* W = (const float*)d_in[1];
    const float* B = (const float*)d_in[2];
    float* O = (float*)d_out;

    const size_t xb_bytes = (size_t)NN * DD * sizeof(__bf16);      // 4 MiB
    const size_t wt_bytes = (size_t)EE * DD * DD * sizeof(__bf16); // 2 MiB

    if (ws_size >= xb_bytes + wt_bytes) {
        __bf16* Xb  = (__bf16*)d_ws;
        __bf16* WTs = (__bf16*)((char*)d_ws + xb_bytes);
        cvt_x<<<NN * DD / 8 / 256, 256, 0, stream>>>(X, Xb);
        cvt_wt<<<EE, 256, 0, stream>>>(W, WTs);
        experts_gemm_ls<<<(NN / 128) * (EE / EG), 512, 0, stream>>>(Xb, WTs, B, O);
    } else {
        experts_gemm_fb<<<(NN / 128) * EE, 256, 0, stream>>>(X, W, B, O);
    }
}

// Round 19
// 118.458 us; speedup vs baseline: 1.2409x; 1.1401x over previous
//
#include <hip/hip_runtime.h>
#include <hip/hip_bf16.h>

typedef __bf16 bf16x8 __attribute__((ext_vector_type(8)));
typedef __bf16 bf16x4 __attribute__((ext_vector_type(4)));
typedef float  f32x4  __attribute__((ext_vector_type(4)));

constexpr int NN = 16384;
constexpr int EE = 64;
constexpr int DD = 128;
constexpr int EG  = 8;     // experts per block

// ---------- pre-pass 1: X f32 -> bf16 row-major [N][D] ----------
__global__ __launch_bounds__(256)
void cvt_x(const float* __restrict__ X, __bf16* __restrict__ Xb) {
    int i = blockIdx.x * 256 + threadIdx.x;
    const float4* src = (const float4*)X;
    float4 v0 = src[2*i], v1 = src[2*i+1];
    bf16x8 p;
    p[0]=(__bf16)v0.x; p[1]=(__bf16)v0.y; p[2]=(__bf16)v0.z; p[3]=(__bf16)v0.w;
    p[4]=(__bf16)v1.x; p[5]=(__bf16)v1.y; p[6]=(__bf16)v1.z; p[7]=(__bf16)v1.w;
    ((bf16x8*)Xb)[i] = p;
}

// ---------- pre-pass 2: W[e][d][f] f32 -> per-expert SWIZZLED bf16 [f][d] ----------
// Element (f,d) at byte (f*256 + d*2) ^ ((f&7)<<4) within expert's 32KB.
// global_load_lds copies linearly; ds_read applies the same XOR (rule #21).
__global__ __launch_bounds__(256)
void cvt_wt(const float* __restrict__ W, __bf16* __restrict__ WTs) {
    __shared__ __bf16 T[DD][DD + 1];
    const int e = blockIdx.x;
    const int t = threadIdx.x;
    const float4* Wg = (const float4*)(W + (size_t)e * DD * DD);
    #pragma unroll
    for (int i = 0; i < 16; ++i) {
        int ft = i * 256 + t;
        int d = ft >> 5, f0 = (ft & 31) * 4;
        float4 v = Wg[ft];
        T[f0+0][d] = (__bf16)v.x;
        T[f0+1][d] = (__bf16)v.y;
        T[f0+2][d] = (__bf16)v.z;
        T[f0+3][d] = (__bf16)v.w;
    }
    __syncthreads();
    char* out = (char*)WTs + (size_t)e * DD * DD * 2;
    #pragma unroll
    for (int i = 0; i < 8; ++i) {
        int ft = i * 256 + t;
        int f = ft >> 4, d0 = (ft & 15) * 8;
        bf16x8 p;
        #pragma unroll
        for (int j = 0; j < 8; ++j) p[j] = T[f][d0 + j];
        int off = f * 256 + d0 * 2;
        off ^= (f & 7) << 4;
        *(bf16x8*)(out + off) = p;
    }
}

__device__ __forceinline__ void gll16(const void* g, void* l) {
    __builtin_amdgcn_global_load_lds(
        (const __attribute__((address_space(1))) void*)g,
        (__attribute__((address_space(3))) void*)l, 16, 0, 0);
}

// ---------- main GEMM: 512 thr / 8 waves, 128 rows x 8 experts ----------
// Wave (wr 0..3, wc 0..1) computes 32 rows x 64 cols per expert.
// Best-known structure (R13, 118.8 us): bias for all 8 experts staged to LDS
// at the prologue (ds_read -> lgkm only; ZERO vm loads in the steady loop,
// so the previous expert's stores drain across the whole compute phase);
// wave-private obuf repack -> 256 B-contiguous stores (write-allocate granule
// plateau); counted vmcnt(8) end-of-iter barrier retires glls only, keeping
// this expert's 8 stores in flight. e-minor block mapping (X reuse in L2).
__global__ __launch_bounds__(512, 1)
void experts_gemm_ls(const __bf16* __restrict__ Xb,
                     const __bf16* __restrict__ WTs,
                     const float* __restrict__ Bias,
                     float* __restrict__ O)
{
    __shared__ __align__(16) char lds[2*32768 + 65536 + 4096]; // Wdbuf|obuf|bias
    const int t    = threadIdx.x;
    const int lane = t & 63, w = t >> 6;          // w 0..7
    const int l15  = lane & 15, kg = lane >> 4;
    const int wr   = w >> 1, wc = w & 1;          // 4 row-groups x 2 col-halves
    const int eg   = blockIdx.x & (EE/EG - 1);
    const int n0   = (blockIdx.x >> 3) * 128;
    const int e0   = eg * EG;
    char* obuf = lds + 65536 + w * 8192;          // wave-private 8 KB
    char* blds = lds + 131072;                    // 8 experts x 512 B bias

    // X fragments, loaded once: rows n0 + wr*32 + m*16 + l15, k = kk*32+kg*8
    bf16x8 a[2][4];
    {
        const __bf16* Xp = Xb + (size_t)(n0 + wr*32 + l15) * DD + kg*8;
        #pragma unroll
        for (int m = 0; m < 2; ++m)
            #pragma unroll
            for (int kk = 0; kk < 4; ++kk)
                a[m][kk] = *(const bf16x8*)(Xp + m*16*DD + kk*32);
    }

    // prologue: stage bias for all EG experts -> LDS (4 KB, one f32x4/thread)
    if (t < 256) {
        f32x4 v = ((const f32x4*)(Bias + e0*DD))[t];
        *(f32x4*)(blds + t*16) = v;
    }

    // prologue: stage W[e0] -> buffer 0 (each wave stages 4 KB via 4 glls)
    {
        const char* src = (const char*)WTs + (size_t)e0 * 32768 + w*4096 + lane*16;
        char* dst = lds + w*4096;
        #pragma unroll
        for (int i = 0; i < 4; ++i) gll16(src + i*1024, dst + i*1024);
    }
    __syncthreads();

    int cur = 0;
    for (int ei = 0; ei < EG; ++ei) {
        const int e = e0 + ei;

        // prefetch next expert's W into the other buffer (stays in flight)
        if (ei + 1 < EG) {
            const char* src = (const char*)WTs + (size_t)(e+1) * 32768 + w*4096 + lane*16;
            char* dst = lds + (cur ^ 1) * 32768 + w*4096;
            #pragma unroll
            for (int i = 0; i < 4; ++i) gll16(src + i*1024, dst + i*1024);
        }

        // bias via LDS (lgkm only — no vmcnt wait in the loop)
        f32x4 acc[2][4];
        #pragma unroll
        for (int n = 0; n < 4; ++n) {
            f32x4 bv = *(const f32x4*)(blds + ei*512 + wc*256 + n*64 + kg*16);
            acc[0][n] = bv; acc[1][n] = bv;
        }

        // compute
        const char* buf = lds + cur * 32768;
        #pragma unroll
        for (int kk = 0; kk < 4; ++kk) {
            bf16x8 b[4];
            #pragma unroll
            for (int n = 0; n < 4; ++n) {
                int f = wc*64 + n*16 + l15;
                int off = f*256 + (kk*32 + kg*8)*2;
                off ^= (l15 & 7) << 4;
                b[n] = *(const bf16x8*)(buf + off);
            }
            #pragma unroll
            for (int m = 0; m < 2; ++m)
                #pragma unroll
                for (int n = 0; n < 4; ++n)
                    acc[m][n] = __builtin_amdgcn_mfma_f32_16x16x32_bf16(
                        b[n], a[m][kk], acc[m][n], 0, 0, 0);
        }

        // stage acc -> wave-private obuf: row = m*16+l15 (0..31), 256 B/row
        #pragma unroll
        for (int m = 0; m < 2; ++m) {
            #pragma unroll
            for (int n = 0; n < 4; ++n) {
                int row = m*16 + l15;
                int off = row*256 + n*64 + kg*16;
                off ^= (row & 7) << 4;
                *(f32x4*)(obuf + off) = acc[m][n];
            }
        }
        // no barrier: same wave reads its own slice (lgkm-ordered)

        // readback + stores: per inst 16 lanes x 16 B = 256 B contiguous per
        // row, 4 rows per inst.
        {
            const int row_off = lane >> 4;       // 0..3
            const int c16 = lane & 15;           // 16 lanes -> 256 B run
            #pragma unroll
            for (int rg = 0; rg < 8; ++rg) {     // 32 rows / 4 per inst
                int row = rg*4 + row_off;
                int off = row*256 + c16*16;
                off ^= (row & 7) << 4;
                f32x4 v = *(const f32x4*)(obuf + off);
                *(f32x4*)(O + (size_t)(n0 + wr*32 + row) * (EE*DD)
                            + e*DD + wc*64 + c16*4) = v;
            }
        }

        // counted barrier: vm queue here = [prev leftovers..., glls(4), stores(8)].
        // vmcnt(8) retires the glls (next W buffer ready) and anything older;
        // keeps the 8 newest (this expert's stores) in flight through the
        // next compute phase.
        if (ei + 1 < EG) {
            __builtin_amdgcn_sched_barrier(0);
            asm volatile("s_waitcnt vmcnt(8)" ::: "memory");
            __builtin_amdgcn_s_barrier();
            __builtin_amdgcn_sched_barrier(0);
        }
        cur ^= 1;
    }
}

// ---------- fallback (round-0 kernel, used if ws too small) ----------
__global__ __launch_bounds__(256, 2)
void experts_gemm_fb(const float* __restrict__ X,
                     const float* __restrict__ W,
                     const float* __restrict__ Bias,
                     float* __restrict__ O)
{
    constexpr int BM = 128;
    __shared__ __align__(16) char lds[BM*DD*2 + DD*DD*2];
    __bf16* As = (__bf16*)lds;
    __bf16* Bs = (__bf16*)(lds + BM*DD*2);

    const int t   = threadIdx.x;
    const int e   = blockIdx.x & (EE - 1);
    const int n0  = (blockIdx.x >> 6) * BM;

    {
        const float4* Xg = (const float4*)(X + (size_t)n0 * DD);
        #pragma unroll
        for (int i = 0; i < 16; ++i) {
            int ft = i * 256 + t;
            float4 v = Xg[ft];
            int n = ft >> 5, d0 = (ft & 31) << 2;
            bf16x4 p;
            p[0]=(__bf16)v.x; p[1]=(__bf16)v.y; p[2]=(__bf16)v.z; p[3]=(__bf16)v.w;
            int off = n * 256 + d0 * 2;
            off ^= (n & 7) << 4;
            *(bf16x4*)((char*)As + off) = p;
        }
    }
    {
        const float4* Wg = (const float4*)(W + (size_t)e * DD * DD);
        #pragma unroll
        for (int i = 0; i < 4; ++i) {
            int bb = i * 256 + t;
            int db = bb >> 5, fb = bb & 31;
            float4 r0 = Wg[(db*4+0)*32 + fb];
            float4 r1 = Wg[(db*4+1)*32 + fb];
            float4 r2 = Wg[(db*4+2)*32 + fb];
            float4 r3 = Wg[(db*4+3)*32 + fb];
            const float* q0=(const float*)&r0; const float* q1=(const float*)&r1;
            const float* q2=(const float*)&r2; const float* q3=(const float*)&r3;
            #pragma unroll
            for (int j = 0; j < 4; ++j) {
                bf16x4 p;
                p[0]=(__bf16)q0[j]; p[1]=(__bf16)q1[j];
                p[2]=(__bf16)q2[j]; p[3]=(__bf16)q3[j];
                int f = fb * 4 + j;
                int off = f * 256 + db * 8;
                off ^= (f & 7) << 4;
                *(bf16x4*)((char*)Bs + off) = p;
            }
        }
    }
    __syncthreads();

    const int lane = t & 63, w = t >> 6;
    const int wr = w >> 1, wc = w & 1;
    const int l15 = lane & 15, kg = lane >> 4;

    f32x4 acc[4][4];
    #pragma unroll
    for (int m = 0; m < 4; ++m)
        #pragma unroll
        for (int n = 0; n < 4; ++n) {
            acc[m][n][0]=0.f; acc[m][n][1]=0.f; acc[m][n][2]=0.f; acc[m][n][3]=0.f;
        }

    float bias[4];
    #pragma unroll
    for (int n = 0; n < 4; ++n) bias[n] = Bias[e*DD + wc*64 + n*16 + l15];

    #pragma unroll
    for (int kk = 0; kk < 4; ++kk) {
        int koff = kk * 32 + kg * 8;
        bf16x8 av[4], bvv[4];
        #pragma unroll
        for (int m = 0; m < 4; ++m) {
            int row = wr*64 + m*16 + l15;
            int off = row * 256 + koff * 2;
            off ^= (row & 7) << 4;
            av[m] = *(const bf16x8*)((const char*)As + off);
        }
        #pragma unroll
        for (int n = 0; n < 4; ++n) {
            int col = wc*64 + n*16 + l15;
            int off = col * 256 + koff * 2;
            off ^= (col & 7) << 4;
            bvv[n] = *(const bf16x8*)((const char*)Bs + off);
        }
        #pragma unroll
        for (int m = 0; m < 4; ++m)
            #pragma unroll
            for (int n = 0; n < 4; ++n)
                acc[m][n] = __builtin_amdgcn_mfma_f32_16x16x32_bf16(
                    av[m], bvv[n], acc[m][n], 0, 0, 0);
    }

    float* Op = O + (size_t)n0 * (EE*DD) + (size_t)e * DD;
    #pragma unroll
    for (int m = 0; m < 4; ++m)
        #pragma unroll
        for (int n = 0; n < 4; ++n) {
            int cg = wc*64 + n*16 + l15;
            #pragma unroll
            for (int r = 0; r < 4; ++r) {
                int rg = wr*64 + m*16 + kg*4 + r;
                Op[(size_t)rg * (EE*DD) + cg] = acc[m][n][r] + bias[n];
            }
        }
}

extern "C" void kernel_launch(void* const* d_in, const int* in_sizes, int n_in,
                              void* d_out, int out_size, void* d_ws, size_t ws_size,
                              hipStream_t stream) {
    const float* X = (const float*)d_in[0];
    const float* W = (const float*)d_in[1];
    const float* B = (const float*)d_in[2];
    float* O = (float*)d_out;

    const size_t xb_bytes = (size_t)NN * DD * sizeof(__bf16);      // 4 MiB
    const size_t wt_bytes = (size_t)EE * DD * DD * sizeof(__bf16); // 2 MiB

    if (ws_size >= xb_bytes + wt_bytes) {
        __bf16* Xb  = (__bf16*)d_ws;
        __bf16* WTs = (__bf16*)((char*)d_ws + xb_bytes);
        cvt_x<<<NN * DD / 8 / 256, 256, 0, stream>>>(X, Xb);
        cvt_wt<<<EE, 256, 0, stream>>>(W, WTs);
        experts_gemm_ls<<<(NN / 128) * (EE / EG), 512, 0, stream>>>(Xb, WTs, B, O);
    } else {
        experts_gemm_fb<<<(NN / 128) * EE, 256, 0, stream>>>(X, W, B, O);
    }
}